// Round 9
// baseline (676.432 us; speedup 1.0000x reference)
//
#include <hip/hip_runtime.h>

typedef unsigned short u16;
typedef unsigned int u32;
typedef __attribute__((ext_vector_type(8))) short short8;
typedef __attribute__((ext_vector_type(4))) float f32x4;
typedef __attribute__((ext_vector_type(4))) u32 u32x4;

#define BKT_SHIFT 6
#define BKT_NODES 64           // nodes per bucket == MLP tile
#define CAP 1536               // slots/bucket (mean 1024, +16 sigma)
#define EPB 4096               // edges per bin block (196 blocks, ~5 recs/bucket/block)
#define NBH 1024               // bin histogram size (pow2 >= nbuck=782)

__device__ inline u16 f2bf(float f){ u32 u=__float_as_uint(f); u32 r=((u>>16)&1u)+0x7fffu; return (u16)((u+r)>>16); }

// ---------- fused: h->bf16 cast (to ws) + weight transpose + edge binning ----------
__global__ __launch_bounds__(256) void k_castbin(
    const int* __restrict__ src, const int* __restrict__ dst,
    int* __restrict__ gcnt, u32* __restrict__ recs_g, int nE, int gB,
    const float* __restrict__ h, u16* __restrict__ hbf, int nh8,
    const float* __restrict__ w1, const float* __restrict__ w2,
    u16* __restrict__ w1t, u16* __restrict__ w2t){
  __shared__ u32 rl[EPB];
  __shared__ int hist[NBH];
  __shared__ int curs[NBH];
  int t = threadIdx.x;
  if ((int)blockIdx.x < gB){
    int e0 = blockIdx.x*EPB;
    for (int i=t;i<NBH;i+=256) hist[i]=0;
    __syncthreads();
    #pragma unroll
    for (int i=0;i<EPB/256;i++){
      int e = e0 + i*256 + t;
      u32 rec = 0xffffffffu;               // sentinel: bucket=1023, impossible
      if (e < nE){
        u32 d = (u32)dst[e];
        u32 s = (u32)src[e];
        u32 bb = d >> BKT_SHIFT;
        rec = (bb<<22) | ((d & (u32)(BKT_NODES-1))<<16) | s;
        atomicAdd(&hist[bb], 1);
      }
      rl[i*256+t] = rec;
    }
    __syncthreads();
    for (int i=t;i<NBH;i+=256){
      int c = hist[i];
      curs[i] = c ? atomicAdd(&gcnt[i], c) : 0;
    }
    __syncthreads();
    #pragma unroll
    for (int i=0;i<EPB/256;i++){
      u32 rec = rl[i*256+t];
      if (rec != 0xffffffffu){
        u32 bb = rec>>22;
        int slot = atomicAdd(&curs[bb], 1);
        if (slot < CAP) recs_g[(size_t)bb*CAP + slot] = rec & 0x3fffffu;
      }
    }
  } else {
    int e = ((int)blockIdx.x - gB)*256 + t;
    if (e < nh8){
      float4 a = *(const float4*)(h + (size_t)e*8);
      float4 b = *(const float4*)(h + (size_t)e*8 + 4);
      u32x4 p;
      p.x = (u32)f2bf(a.x) | ((u32)f2bf(a.y)<<16);
      p.y = (u32)f2bf(a.z) | ((u32)f2bf(a.w)<<16);
      p.z = (u32)f2bf(b.x) | ((u32)f2bf(b.y)<<16);
      p.w = (u32)f2bf(b.z) | ((u32)f2bf(b.w)<<16);
      *(u32x4*)(hbf + (size_t)e*8) = p;
    }
    if (e < 256*128){ int k=e>>7, nn=e&127; w1t[nn*256+k]=f2bf(w1[e]); }
    else { int j=e-256*128; if (j<128*128){ int k=j>>7, nn=j&127; w2t[nn*128+k]=f2bf(w2[j]); } }
  }
}

// ---------- sort-free slab aggregation: LDS fp32 accumulate over unsorted records ----------
// Block = (bucket b, slab s): slab s = bytes [64s,64s+64) of each hbf row (one full
// 64B line). blockIdx&3 == s -> round-robin dispatch pins slab s to XCDs {s,s+4};
// per-XCD random hbf footprint = 3.2MB < 4MB L2. Records processed in ARBITRARY order:
// wave takes 4 recs/iter (16 lanes each), lane loads one u32 (2 bf16 cols) of the
// 64B line, ds_add_f32 into acc[dstLow][2c(,+1)]. All loads independent -> pure
// stream, TLP covers L2 latency (no index-chain serialization, no sort dispatch).
__global__ __launch_bounds__(256) void k_aggs(
    const u32* __restrict__ hbfw, const u32* __restrict__ recs_g,
    const int* __restrict__ gcnt, u32* __restrict__ aggS,
    int n, int npad){
  __shared__ float acc[BKT_NODES][32];    // 8 KB fp32 accumulators (this slab's 32 cols)
  __shared__ u32 rl[CAP];                 // 6 KB record stage
  __shared__ int hist[BKT_NODES];
  int bid = (int)blockIdx.x;
  int s = bid & 3;
  int b = bid >> 2;
  int t = threadIdx.x;
  int cnt = gcnt[b]; if (cnt > CAP) cnt = CAP;
  const u32* rp = recs_g + (size_t)b*CAP;

  for (int i=t; i<BKT_NODES*32; i+=256) ((float*)acc)[i] = 0.f;
  if (t < BKT_NODES) hist[t] = 0;
  for (int i=t; i<cnt; i+=256) rl[i] = rp[i];
  __syncthreads();

  int wave = t>>6, lane = t&63, q = lane>>4, c = lane&15;
  #pragma unroll 2
  for (int i = wave*4 + q; i < cnt; i += 16){
    u32 r = rl[i];                         // 16-lane broadcast read
    int dl  = (int)((r>>16) & (BKT_NODES-1));
    int sidx= (int)(r & 0xffffu);
    u32 v = hbfw[(size_t)sidx*64 + s*16 + c];
    union{u32 u; float f;} lo,hi; lo.u = v<<16; hi.u = v & 0xffff0000u;
    atomicAdd(&acc[dl][2*c  ], lo.f);
    atomicAdd(&acc[dl][2*c+1], hi.f);
    if (c == 0) atomicAdd(&hist[dl], 1);
  }
  __syncthreads();

  // write slab-major agg (bf16 pairs), nontemporal to keep slab L2-resident
  for (int i=t; i<BKT_NODES*16; i+=256){
    int nl = i>>4, cc = i&15;
    int node = b*BKT_NODES + nl;
    if (node < n){
      int dg = hist[nl];
      float inv = 1.f/(float)(dg>0?dg:1);
      u32 pv = (u32)f2bf(acc[nl][2*cc]*inv) | ((u32)f2bf(acc[nl][2*cc+1]*inv)<<16);
      __builtin_nontemporal_store(pv, aggS + ((size_t)s*npad + node)*16 + cc);
    }
  }
}

// ---------- dense MLP: 8 waves, wave owns 16 output cols ----------
__global__ __launch_bounds__(512) void k_mlp(
    const u16* __restrict__ hbf, const u32* __restrict__ aggS,
    const u16* __restrict__ w1t, const u16* __restrict__ w2t,
    const float* __restrict__ b1, const float* __restrict__ b2,
    float* __restrict__ out, int n, int npad){
  __shared__ __align__(16) u16 xs[64*264];
  int t = threadIdx.x;
  int node0 = blockIdx.x*64;
  int wave=t>>6, lane=t&63, quad=lane>>4, l16=lane&15;

  const u16* w1p = w1t + (size_t)(wave*16 + l16)*256 + quad*8;
  short8 wb1[8];
  #pragma unroll
  for (int ks=0;ks<8;ks++) wb1[ks] = *(const short8*)(w1p + ks*32);

  // stage: 64 rows x 32 chunks; c8<16 = h half (hbf), else agg slab q=c8-16
  #pragma unroll
  for (int i=0;i<4;i++){
    int idx = i*512 + t;
    int row = idx>>5, c8 = idx&31;
    int node = node0 + row;
    u32x4 v = {0,0,0,0};
    if (node < n){
      if (c8 < 16) v = *(const u32x4*)(hbf + (size_t)node*128 + c8*8);
      else {
        int q = c8-16;   // u32 cols [4q,4q+4): slab q>>2, in-slab offset (q&3)*4
        v = *(const u32x4*)(aggS + ((size_t)(q>>2)*npad + node)*16 + (q&3)*4);
      }
    }
    *(u32x4*)(&xs[row*264 + c8*8]) = v;
  }
  __syncthreads();

  f32x4 acc[4];
  #pragma unroll
  for (int m=0;m<4;m++) acc[m]=(f32x4){0,0,0,0};
  #pragma unroll
  for (int ks=0;ks<8;ks++){
    #pragma unroll
    for (int m=0;m<4;m++){
      short8 av = *(const short8*)(&xs[(m*16+l16)*264 + ks*32 + quad*8]);
      acc[m] = __builtin_amdgcn_mfma_f32_16x16x32_bf16(av, wb1[ks], acc[m],0,0,0);
    }
  }

  const u16* w2p = w2t + (size_t)(wave*16 + l16)*128 + quad*8;
  short8 wb2[4];
  #pragma unroll
  for (int ks=0;ks<4;ks++) wb2[ks] = *(const short8*)(w2p + ks*32);
  __syncthreads();   // layer-1 a-frag reads done before X1 overwrites cols 0..127

  float bias = b1[wave*16 + l16];
  #pragma unroll
  for (int m=0;m<4;m++){
    #pragma unroll
    for (int r=0;r<4;r++){
      int row = m*16 + quad*4 + r;
      float v0 = acc[m][r] + bias; v0 = v0>0.f ? v0 : 0.f;
      xs[row*264 + wave*16 + l16] = f2bf(v0);
    }
  }
  __syncthreads();

  f32x4 acc2[4];
  #pragma unroll
  for (int m=0;m<4;m++) acc2[m]=(f32x4){0,0,0,0};
  #pragma unroll
  for (int ks=0;ks<4;ks++){
    #pragma unroll
    for (int m=0;m<4;m++){
      short8 av = *(const short8*)(&xs[(m*16+l16)*264 + ks*32 + quad*8]);
      acc2[m] = __builtin_amdgcn_mfma_f32_16x16x32_bf16(av, wb2[ks], acc2[m],0,0,0);
    }
  }
  float c0 = b2[wave*16 + l16];
  #pragma unroll
  for (int m=0;m<4;m++){
    #pragma unroll
    for (int r=0;r<4;r++){
      int node = node0 + m*16 + quad*4 + r;
      if (node<n){
        float v0 = acc2[m][r]+c0; v0 = v0>0.f?v0:0.f;
        out[(size_t)node*128 + wave*16 + l16] = v0;
      }
    }
  }
}

extern "C" void kernel_launch(void* const* d_in, const int* in_sizes, int n_in,
                              void* d_out, int out_size, void* d_ws, size_t ws_size,
                              hipStream_t stream){
  const float* h  = (const float*)d_in[0];
  const int*   ei = (const int*)d_in[1];
  const float* W1 = (const float*)d_in[2];
  const float* b1 = (const float*)d_in[3];
  const float* W2 = (const float*)d_in[4];
  const float* b2 = (const float*)d_in[5];
  float* out = (float*)d_out;
  int n  = in_sizes[0] / 128;
  int nE = in_sizes[1] / 2;
  const int* srcI = ei;
  const int* dstI = ei + nE;
  int nbuck = (n + BKT_NODES - 1) >> BKT_SHIFT;   // 782
  int npad  = (n + 63) & ~63;

  // workspace layout — ~31 MB
  char* ws = (char*)d_ws;
  u32* recs = (u32*)ws;                               // nbuck*CAP*4 = 4.80 MB
  size_t off = (size_t)nbuck*CAP*4;
  int* gcnt = (int*)(ws + off); off += 4096;          // NBH ints
  u16* hbf  = (u16*)(ws + off); off += (size_t)n*256; // n x 128 bf16 = 12.8 MB
  off = (off + 255) & ~(size_t)255;
  u32* aggS = (u32*)(ws + off); off += (size_t)4*npad*64;      // 12.8 MB slab-major
  off = (off + 15) & ~(size_t)15;
  u16* w1t  = (u16*)(ws + off);                       // 128x256 bf16
  u16* w2t  = (u16*)(ws + off + 65536);               // 128x128 bf16

  hipMemsetAsync(gcnt, 0, NBH*sizeof(int), stream);
  int gB = (nE + EPB - 1)/EPB;                        // 196 bin blocks (first)
  int nh8 = n*16;
  int castN = nh8 > 49152 ? nh8 : 49152;
  int gC = (castN + 255)/256;
  k_castbin<<<gB+gC, 256, 0, stream>>>(srcI, dstI, gcnt, recs, nE, gB,
                                       h, hbf, nh8, W1, W2, w1t, w2t);
  k_aggs<<<nbuck*4, 256, 0, stream>>>((const u32*)hbf, recs, gcnt, aggS, n, npad);
  k_mlp<<<nbuck, 512, 0, stream>>>(hbf, aggS, w1t, w2t, b1, b2, out, n, npad);
}

// Round 10
// 159.983 us; speedup vs baseline: 4.2282x; 4.2282x over previous
//
#include <hip/hip_runtime.h>

typedef unsigned short u16;
typedef unsigned int u32;
typedef __attribute__((ext_vector_type(8))) short short8;
typedef __attribute__((ext_vector_type(4))) float f32x4;
typedef __attribute__((ext_vector_type(4))) u32 u32x4;

#define BKT_SHIFT 6
#define BKT_NODES 64           // nodes per bucket == MLP tile
#define CAP 1536               // slots/bucket (mean 1024, +16 sigma)
#define EPB 4096               // edges per bin block (196 blocks, ~5 recs/bucket/block)
#define NBH 1024               // bin histogram size (pow2 >= nbuck=782)

__device__ inline u16 f2bf(float f){ u32 u=__float_as_uint(f); u32 r=((u>>16)&1u)+0x7fffu; return (u16)((u+r)>>16); }

// ---------- fused: h->bf16 cast (to ws) + weight transpose + edge binning ----------
__global__ __launch_bounds__(256) void k_castbin(
    const int* __restrict__ src, const int* __restrict__ dst,
    int* __restrict__ gcnt, u32* __restrict__ recs_g, int nE, int gB,
    const float* __restrict__ h, u16* __restrict__ hbf, int nh8,
    const float* __restrict__ w1, const float* __restrict__ w2,
    u16* __restrict__ w1t, u16* __restrict__ w2t){
  __shared__ u32 rl[EPB];
  __shared__ int hist[NBH];
  __shared__ int curs[NBH];
  int t = threadIdx.x;
  if ((int)blockIdx.x < gB){
    int e0 = blockIdx.x*EPB;
    for (int i=t;i<NBH;i+=256) hist[i]=0;
    __syncthreads();
    #pragma unroll
    for (int i=0;i<EPB/256;i++){
      int e = e0 + i*256 + t;
      u32 rec = 0xffffffffu;               // sentinel: bucket=1023, impossible
      if (e < nE){
        u32 d = (u32)dst[e];
        u32 s = (u32)src[e];
        u32 bb = d >> BKT_SHIFT;
        rec = (bb<<22) | ((d & (u32)(BKT_NODES-1))<<16) | s;
        atomicAdd(&hist[bb], 1);
      }
      rl[i*256+t] = rec;
    }
    __syncthreads();
    for (int i=t;i<NBH;i+=256){
      int c = hist[i];
      curs[i] = c ? atomicAdd(&gcnt[i], c) : 0;
    }
    __syncthreads();
    #pragma unroll
    for (int i=0;i<EPB/256;i++){
      u32 rec = rl[i*256+t];
      if (rec != 0xffffffffu){
        u32 bb = rec>>22;
        int slot = atomicAdd(&curs[bb], 1);
        if (slot < CAP) recs_g[(size_t)bb*CAP + slot] = rec & 0x3fffffu;
      }
    }
  } else {
    int e = ((int)blockIdx.x - gB)*256 + t;
    if (e < nh8){
      float4 a = *(const float4*)(h + (size_t)e*8);
      float4 b = *(const float4*)(h + (size_t)e*8 + 4);
      u32x4 p;
      p.x = (u32)f2bf(a.x) | ((u32)f2bf(a.y)<<16);
      p.y = (u32)f2bf(a.z) | ((u32)f2bf(a.w)<<16);
      p.z = (u32)f2bf(b.x) | ((u32)f2bf(b.y)<<16);
      p.w = (u32)f2bf(b.z) | ((u32)f2bf(b.w)<<16);
      *(u32x4*)(hbf + (size_t)e*8) = p;
    }
    if (e < 256*128){ int k=e>>7, nn=e&127; w1t[nn*256+k]=f2bf(w1[e]); }
    else { int j=e-256*128; if (j<128*128){ int k=j>>7, nn=j&127; w2t[nn*128+k]=f2bf(w2[j]); } }
  }
}

// ---------- per-bucket: LDS counting sort + global_load_lds gather-mean ----------
// Block = bucket (64 nodes), 4 waves, wave owns 16 consecutive nodes.
// Gather engine: global_load_lds size=16 — per issue, 16-lane groups each pull 16B
// of a DIFFERENT hbf row (per-lane global addr) into contiguous LDS: 4 issues = 16
// rows (4KB) in flight, zero VGPR liveness, drained by one vmcnt(0). Accumulate via
// ds_read_b128 (lane owns 4 u32 cols x 4 row-groups) + butterfly reduce.
__global__ __launch_bounds__(256) void k_aggf(
    const u32* __restrict__ hbfw, const u32* __restrict__ recs_g,
    const int* __restrict__ gcnt, u32* __restrict__ outw, int n){
  __shared__ __align__(16) char smem[20224];
  u32* stage = (u32*)smem;                 // [0,6144)  sort pass only
  u32* gbuf  = (u32*)smem;                 // [0,16384) gather buffers (aliases stage)
  u16* srt   = (u16*)(smem + 16384);       // 3072 B
  int* hist  = (int*)(smem + 19456);
  int* scn   = (int*)(smem + 19712);
  int* cur   = (int*)(smem + 19968);
  int b = blockIdx.x, t = threadIdx.x;
  int cnt = gcnt[b]; if (cnt > CAP) cnt = CAP;
  const u32* rp = recs_g + (size_t)b*CAP;

  if (t < BKT_NODES) hist[t] = 0;
  __syncthreads();
  for (int i=t; i<cnt; i+=256){
    u32 r = rp[i];
    stage[i] = r;
    atomicAdd(&hist[(r>>16)&(BKT_NODES-1)], 1);
  }
  __syncthreads();
  if (t < BKT_NODES){                      // wave 0: shfl inclusive scan
    int v = hist[t];
    int s = v;
    #pragma unroll
    for (int d=1; d<64; d<<=1){
      int o = __shfl_up(s, d, 64);
      if (t >= d) s += o;
    }
    scn[t] = s;
    cur[t] = s - v;
  }
  __syncthreads();
  for (int i=t; i<cnt; i+=256){
    u32 r = stage[i];
    int slot = atomicAdd(&cur[(r>>16)&(BKT_NODES-1)], 1);
    srt[slot] = (u16)(r & 0xffffu);
  }
  __syncthreads();                         // also fences stage->gbuf alias reuse

  int wave = t>>6, lane = t&63;
  int j2 = lane>>4, c = lane&15;           // row-group, col-group
  u32* lb = gbuf + wave*1024;              // 4KB per wave (16 rows x 256B)
  int node0 = b*BKT_NODES;

  for (int i=0;i<16;i++){
    int nl = wave*16 + i;
    int node = node0 + nl;
    if (node >= n) break;                  // wave-uniform
    int deg = hist[nl];
    int st  = scn[nl] - deg;
    float a8[8];
    #pragma unroll
    for (int q=0;q<8;q++) a8[q] = 0.f;
    for (int b0=0; b0<deg; b0+=16){
      #pragma unroll
      for (int k=0;k<4;k++){               // 4 issues x 4 rows = 16 rows in flight
        int jr = b0 + k*4 + j2;
        int jc = jr < deg ? jr : deg-1;
        int sidx = (int)srt[st + jc];
        const u32* gp = hbfw + (size_t)sidx*64 + c*4;
        __builtin_amdgcn_global_load_lds(
            (const __attribute__((address_space(1))) u32*)gp,
            (__attribute__((address_space(3))) u32*)(lb + k*256), 16, 0, 0);
      }
      asm volatile("s_waitcnt vmcnt(0)" ::: "memory");
      __builtin_amdgcn_sched_barrier(0);
      #pragma unroll
      for (int k2=0;k2<4;k2++){
        int r = k2*4 + j2;
        float m = (b0 + r < deg) ? 1.f : 0.f;
        u32x4 v = *(const u32x4*)(lb + r*64 + c*4);
        #pragma unroll
        for (int q=0;q<4;q++){
          u32 u = v[q];
          union{u32 w; float f;} lo,hi; lo.w = u<<16; hi.w = u & 0xffff0000u;
          a8[2*q]   += m*lo.f;
          a8[2*q+1] += m*hi.f;
        }
      }
    }
    // reduce across the 4 row-groups (lanes c, c+16, c+32, c+48)
    #pragma unroll
    for (int q=0;q<8;q++){
      float x = a8[q];
      x += __shfl_xor(x, 16, 64);
      x += __shfl_xor(x, 32, 64);
      a8[q] = x;
    }
    if (lane < 16){
      float inv = 1.f/(float)(deg>0?deg:1);
      u32x4 w;
      w.x = (u32)f2bf(a8[0]*inv) | ((u32)f2bf(a8[1]*inv)<<16);
      w.y = (u32)f2bf(a8[2]*inv) | ((u32)f2bf(a8[3]*inv)<<16);
      w.z = (u32)f2bf(a8[4]*inv) | ((u32)f2bf(a8[5]*inv)<<16);
      w.w = (u32)f2bf(a8[6]*inv) | ((u32)f2bf(a8[7]*inv)<<16);
      *(u32x4*)(outw + (size_t)node*128 + 64 + c*4) = w;
    }
  }
}

// ---------- dense MLP: 8 waves, wave owns 16 output cols; reads h half + agg stash ----------
__global__ __launch_bounds__(512) void k_mlp(
    const u16* __restrict__ hbf, const u32* __restrict__ outw_in,
    const u16* __restrict__ w1t, const u16* __restrict__ w2t,
    const float* __restrict__ b1, const float* __restrict__ b2,
    float* __restrict__ out, int n){
  __shared__ __align__(16) u16 xs[64*264];
  int t = threadIdx.x;
  int node0 = blockIdx.x*64;
  int wave=t>>6, lane=t&63, quad=lane>>4, l16=lane&15;

  const u16* w1p = w1t + (size_t)(wave*16 + l16)*256 + quad*8;
  short8 wb1[8];
  #pragma unroll
  for (int ks=0;ks<8;ks++) wb1[ks] = *(const short8*)(w1p + ks*32);

  // stage: 64 rows x 32 chunks; c8<16 from hbf (h half), else agg stash in out rows
  #pragma unroll
  for (int i=0;i<4;i++){
    int idx = i*512 + t;
    int row = idx>>5, c8 = idx&31;
    int node = node0 + row;
    u32x4 v = {0,0,0,0};
    if (node < n){
      if (c8 < 16) v = *(const u32x4*)(hbf + (size_t)node*128 + c8*8);
      else         v = *(const u32x4*)(outw_in + (size_t)node*128 + 64 + (c8-16)*4);
    }
    *(u32x4*)(&xs[row*264 + c8*8]) = v;
  }
  __syncthreads();

  f32x4 acc[4];
  #pragma unroll
  for (int m=0;m<4;m++) acc[m]=(f32x4){0,0,0,0};
  #pragma unroll
  for (int ks=0;ks<8;ks++){
    #pragma unroll
    for (int m=0;m<4;m++){
      short8 av = *(const short8*)(&xs[(m*16+l16)*264 + ks*32 + quad*8]);
      acc[m] = __builtin_amdgcn_mfma_f32_16x16x32_bf16(av, wb1[ks], acc[m],0,0,0);
    }
  }

  const u16* w2p = w2t + (size_t)(wave*16 + l16)*128 + quad*8;
  short8 wb2[4];
  #pragma unroll
  for (int ks=0;ks<4;ks++) wb2[ks] = *(const short8*)(w2p + ks*32);
  __syncthreads();   // layer-1 a-frag reads done before X1 overwrites cols 0..127

  float bias = b1[wave*16 + l16];
  #pragma unroll
  for (int m=0;m<4;m++){
    #pragma unroll
    for (int r=0;r<4;r++){
      int row = m*16 + quad*4 + r;
      float v0 = acc[m][r] + bias; v0 = v0>0.f ? v0 : 0.f;
      xs[row*264 + wave*16 + l16] = f2bf(v0);
    }
  }
  __syncthreads();

  f32x4 acc2[4];
  #pragma unroll
  for (int m=0;m<4;m++) acc2[m]=(f32x4){0,0,0,0};
  #pragma unroll
  for (int ks=0;ks<4;ks++){
    #pragma unroll
    for (int m=0;m<4;m++){
      short8 av = *(const short8*)(&xs[(m*16+l16)*264 + ks*32 + quad*8]);
      acc2[m] = __builtin_amdgcn_mfma_f32_16x16x32_bf16(av, wb2[ks], acc2[m],0,0,0);
    }
  }
  float c0 = b2[wave*16 + l16];
  #pragma unroll
  for (int m=0;m<4;m++){
    #pragma unroll
    for (int r=0;r<4;r++){
      int node = node0 + m*16 + quad*4 + r;
      if (node<n){
        float v0 = acc2[m][r]+c0; v0 = v0>0.f?v0:0.f;
        out[(size_t)node*128 + wave*16 + l16] = v0;
      }
    }
  }
}

extern "C" void kernel_launch(void* const* d_in, const int* in_sizes, int n_in,
                              void* d_out, int out_size, void* d_ws, size_t ws_size,
                              hipStream_t stream){
  const float* h  = (const float*)d_in[0];
  const int*   ei = (const int*)d_in[1];
  const float* W1 = (const float*)d_in[2];
  const float* b1 = (const float*)d_in[3];
  const float* W2 = (const float*)d_in[4];
  const float* b2 = (const float*)d_in[5];
  float* out = (float*)d_out;
  u32* outw  = (u32*)d_out;
  int n  = in_sizes[0] / 128;
  int nE = in_sizes[1] / 2;
  const int* srcI = ei;
  const int* dstI = ei + nE;
  int nbuck = (n + BKT_NODES - 1) >> BKT_SHIFT;   // 782

  // workspace layout — ~18 MB (recs + gcnt + hbf + transposed weights)
  char* ws = (char*)d_ws;
  u32* recs = (u32*)ws;                               // nbuck*CAP*4 = 4.80 MB
  size_t off = (size_t)nbuck*CAP*4;
  int* gcnt = (int*)(ws + off); off += 4096;          // NBH ints
  u16* hbf  = (u16*)(ws + off); off += (size_t)n*256; // n x 128 bf16 = 12.8 MB
  off = (off + 15) & ~(size_t)15;
  u16* w1t  = (u16*)(ws + off);                       // 128x256 bf16
  u16* w2t  = (u16*)(ws + off + 65536);               // 128x128 bf16

  hipMemsetAsync(gcnt, 0, NBH*sizeof(int), stream);
  int gB = (nE + EPB - 1)/EPB;                        // 196 bin blocks (first)
  int nh8 = n*16;
  int castN = nh8 > 49152 ? nh8 : 49152;
  int gC = (castN + 255)/256;
  k_castbin<<<gB+gC, 256, 0, stream>>>(srcI, dstI, gcnt, recs, nE, gB,
                                       h, hbf, nh8, W1, W2, w1t, w2t);
  k_aggf<<<nbuck, 256, 0, stream>>>((const u32*)hbf, recs, gcnt, outw, n);
  k_mlp<<<nbuck, 512, 0, stream>>>(hbf, outw, w1t, w2t, b1, b2, out, n);
}

// Round 11
// 157.322 us; speedup vs baseline: 4.2997x; 1.0169x over previous
//
#include <hip/hip_runtime.h>

typedef unsigned short u16;
typedef unsigned int u32;
typedef __attribute__((ext_vector_type(8))) short short8;
typedef __attribute__((ext_vector_type(4))) float f32x4;
typedef __attribute__((ext_vector_type(4))) u32 u32x4;

#define BKT_SHIFT 6
#define BKT_NODES 64           // nodes per bucket == MLP tile
#define CAP 1536               // slots/bucket (mean 1024, +16 sigma)
#define EPB 4096               // edges per bin block (196 blocks, ~5 recs/bucket/block)
#define NBH 1024               // bin histogram size (pow2 >= nbuck=782)

__device__ inline u16 f2bf(float f){ u32 u=__float_as_uint(f); u32 r=((u>>16)&1u)+0x7fffu; return (u16)((u+r)>>16); }

// ---------- fused: h->bf16 cast (to ws) + weight transpose + edge binning ----------
__global__ __launch_bounds__(256) void k_castbin(
    const int* __restrict__ src, const int* __restrict__ dst,
    int* __restrict__ gcnt, u32* __restrict__ recs_g, int nE, int gB,
    const float* __restrict__ h, u16* __restrict__ hbf, int nh8,
    const float* __restrict__ w1, const float* __restrict__ w2,
    u16* __restrict__ w1t, u16* __restrict__ w2t){
  __shared__ u32 rl[EPB];
  __shared__ int hist[NBH];
  __shared__ int curs[NBH];
  int t = threadIdx.x;
  if ((int)blockIdx.x < gB){
    int e0 = blockIdx.x*EPB;
    for (int i=t;i<NBH;i+=256) hist[i]=0;
    __syncthreads();
    #pragma unroll
    for (int i=0;i<EPB/256;i++){
      int e = e0 + i*256 + t;
      u32 rec = 0xffffffffu;               // sentinel: bucket=1023, impossible
      if (e < nE){
        u32 d = (u32)dst[e];
        u32 s = (u32)src[e];
        u32 bb = d >> BKT_SHIFT;
        rec = (bb<<22) | ((d & (u32)(BKT_NODES-1))<<16) | s;
        atomicAdd(&hist[bb], 1);
      }
      rl[i*256+t] = rec;
    }
    __syncthreads();
    for (int i=t;i<NBH;i+=256){
      int c = hist[i];
      curs[i] = c ? atomicAdd(&gcnt[i], c) : 0;
    }
    __syncthreads();
    #pragma unroll
    for (int i=0;i<EPB/256;i++){
      u32 rec = rl[i*256+t];
      if (rec != 0xffffffffu){
        u32 bb = rec>>22;
        int slot = atomicAdd(&curs[bb], 1);
        if (slot < CAP) recs_g[(size_t)bb*CAP + slot] = rec & 0x3fffffu;
      }
    }
  } else {
    int e = ((int)blockIdx.x - gB)*256 + t;
    if (e < nh8){
      float4 a = *(const float4*)(h + (size_t)e*8);
      float4 b = *(const float4*)(h + (size_t)e*8 + 4);
      u32x4 p;
      p.x = (u32)f2bf(a.x) | ((u32)f2bf(a.y)<<16);
      p.y = (u32)f2bf(a.z) | ((u32)f2bf(a.w)<<16);
      p.z = (u32)f2bf(b.x) | ((u32)f2bf(b.y)<<16);
      p.w = (u32)f2bf(b.z) | ((u32)f2bf(b.w)<<16);
      *(u32x4*)(hbf + (size_t)e*8) = p;
    }
    if (e < 256*128){ int k=e>>7, nn=e&127; w1t[nn*256+k]=f2bf(w1[e]); }
    else { int j=e-256*128; if (j<128*128){ int k=j>>7, nn=j&127; w2t[nn*128+k]=f2bf(w2[j]); } }
  }
}

// ---------- per-bucket: LDS counting sort + global_load_lds gather-mean ----------
// Block = bucket (64 nodes), 512 thr = 8 waves, wave owns 8 consecutive nodes.
// 8 waves (vs R10's 4) doubles resident waves/CU (~24): the synchronous
// {issue 4 global_load_lds -> vmcnt(0) -> accumulate} cycle has ~3:1 wait:work,
// so 6 waves/SIMD cover the drain latency (R10's 3 could not -> 2.0 TB/s).
// Gather engine: per issue, 16-lane groups pull 16B of DIFFERENT hbf rows (per-lane
// global addr) into contiguous LDS; 4 issues = 16 rows (4KB) in flight, zero VGPR
// liveness. Accumulate via ds_read b128 + butterfly reduce.
__global__ __launch_bounds__(512) void k_aggf(
    const u32* __restrict__ hbfw, const u32* __restrict__ recs_g,
    const int* __restrict__ gcnt, u32* __restrict__ outw, int n){
  __shared__ __align__(16) char smem[36608];
  u32* stage = (u32*)smem;                 // [0,6144)  sort pass only
  u32* gbuf  = (u32*)smem;                 // [0,32768) gather buffers (alias stage)
  u16* srt   = (u16*)(smem + 32768);       // 3072 B
  int* hist  = (int*)(smem + 35840);
  int* scn   = (int*)(smem + 36096);
  int* cur   = (int*)(smem + 36352);
  int b = blockIdx.x, t = threadIdx.x;
  int cnt = gcnt[b]; if (cnt > CAP) cnt = CAP;
  const u32* rp = recs_g + (size_t)b*CAP;

  if (t < BKT_NODES) hist[t] = 0;
  __syncthreads();
  for (int i=t; i<cnt; i+=512){
    u32 r = rp[i];
    stage[i] = r;
    atomicAdd(&hist[(r>>16)&(BKT_NODES-1)], 1);
  }
  __syncthreads();
  if (t < BKT_NODES){                      // wave 0: shfl inclusive scan
    int v = hist[t];
    int s = v;
    #pragma unroll
    for (int d=1; d<64; d<<=1){
      int o = __shfl_up(s, d, 64);
      if (t >= d) s += o;
    }
    scn[t] = s;
    cur[t] = s - v;
  }
  __syncthreads();
  for (int i=t; i<cnt; i+=512){
    u32 r = stage[i];
    int slot = atomicAdd(&cur[(r>>16)&(BKT_NODES-1)], 1);
    srt[slot] = (u16)(r & 0xffffu);
  }
  __syncthreads();                         // also fences stage->gbuf alias reuse

  int wave = t>>6, lane = t&63;
  int j2 = lane>>4, c = lane&15;           // row-group, col-group
  u32* lb = gbuf + wave*1024;              // 4KB per wave (16 rows x 256B)
  int node0 = b*BKT_NODES;

  for (int i=0;i<8;i++){
    int nl = wave*8 + i;
    int node = node0 + nl;
    if (node >= n) break;                  // wave-uniform
    int deg = hist[nl];
    int st  = scn[nl] - deg;
    float a8[8];
    #pragma unroll
    for (int q=0;q<8;q++) a8[q] = 0.f;
    for (int b0=0; b0<deg; b0+=16){
      #pragma unroll
      for (int k=0;k<4;k++){               // 4 issues x 4 rows = 16 rows in flight
        int jr = b0 + k*4 + j2;
        int jc = jr < deg ? jr : deg-1;
        int sidx = (int)srt[st + jc];
        const u32* gp = hbfw + (size_t)sidx*64 + c*4;
        __builtin_amdgcn_global_load_lds(
            (const __attribute__((address_space(1))) u32*)gp,
            (__attribute__((address_space(3))) u32*)(lb + k*256), 16, 0, 0);
      }
      asm volatile("s_waitcnt vmcnt(0)" ::: "memory");
      __builtin_amdgcn_sched_barrier(0);
      #pragma unroll
      for (int k2=0;k2<4;k2++){
        int r = k2*4 + j2;
        float m = (b0 + r < deg) ? 1.f : 0.f;
        u32x4 v = *(const u32x4*)(lb + r*64 + c*4);
        #pragma unroll
        for (int q=0;q<4;q++){
          u32 u = v[q];
          union{u32 w; float f;} lo,hi; lo.w = u<<16; hi.w = u & 0xffff0000u;
          a8[2*q]   += m*lo.f;
          a8[2*q+1] += m*hi.f;
        }
      }
    }
    // reduce across the 4 row-groups (lanes c, c+16, c+32, c+48)
    #pragma unroll
    for (int q=0;q<8;q++){
      float x = a8[q];
      x += __shfl_xor(x, 16, 64);
      x += __shfl_xor(x, 32, 64);
      a8[q] = x;
    }
    if (lane < 16){
      float inv = 1.f/(float)(deg>0?deg:1);
      u32x4 w;
      w.x = (u32)f2bf(a8[0]*inv) | ((u32)f2bf(a8[1]*inv)<<16);
      w.y = (u32)f2bf(a8[2]*inv) | ((u32)f2bf(a8[3]*inv)<<16);
      w.z = (u32)f2bf(a8[4]*inv) | ((u32)f2bf(a8[5]*inv)<<16);
      w.w = (u32)f2bf(a8[6]*inv) | ((u32)f2bf(a8[7]*inv)<<16);
      *(u32x4*)(outw + (size_t)node*128 + 64 + c*4) = w;
    }
  }
}

// ---------- dense MLP: 8 waves, wave owns 16 output cols; reads h half + agg stash ----------
__global__ __launch_bounds__(512) void k_mlp(
    const u16* __restrict__ hbf, const u32* __restrict__ outw_in,
    const u16* __restrict__ w1t, const u16* __restrict__ w2t,
    const float* __restrict__ b1, const float* __restrict__ b2,
    float* __restrict__ out, int n){
  __shared__ __align__(16) u16 xs[64*264];
  int t = threadIdx.x;
  int node0 = blockIdx.x*64;
  int wave=t>>6, lane=t&63, quad=lane>>4, l16=lane&15;

  const u16* w1p = w1t + (size_t)(wave*16 + l16)*256 + quad*8;
  short8 wb1[8];
  #pragma unroll
  for (int ks=0;ks<8;ks++) wb1[ks] = *(const short8*)(w1p + ks*32);

  // stage: 64 rows x 32 chunks; c8<16 from hbf (h half), else agg stash in out rows
  #pragma unroll
  for (int i=0;i<4;i++){
    int idx = i*512 + t;
    int row = idx>>5, c8 = idx&31;
    int node = node0 + row;
    u32x4 v = {0,0,0,0};
    if (node < n){
      if (c8 < 16) v = *(const u32x4*)(hbf + (size_t)node*128 + c8*8);
      else         v = *(const u32x4*)(outw_in + (size_t)node*128 + 64 + (c8-16)*4);
    }
    *(u32x4*)(&xs[row*264 + c8*8]) = v;
  }
  __syncthreads();

  f32x4 acc[4];
  #pragma unroll
  for (int m=0;m<4;m++) acc[m]=(f32x4){0,0,0,0};
  #pragma unroll
  for (int ks=0;ks<8;ks++){
    #pragma unroll
    for (int m=0;m<4;m++){
      short8 av = *(const short8*)(&xs[(m*16+l16)*264 + ks*32 + quad*8]);
      acc[m] = __builtin_amdgcn_mfma_f32_16x16x32_bf16(av, wb1[ks], acc[m],0,0,0);
    }
  }

  const u16* w2p = w2t + (size_t)(wave*16 + l16)*128 + quad*8;
  short8 wb2[4];
  #pragma unroll
  for (int ks=0;ks<4;ks++) wb2[ks] = *(const short8*)(w2p + ks*32);
  __syncthreads();   // layer-1 a-frag reads done before X1 overwrites cols 0..127

  float bias = b1[wave*16 + l16];
  #pragma unroll
  for (int m=0;m<4;m++){
    #pragma unroll
    for (int r=0;r<4;r++){
      int row = m*16 + quad*4 + r;
      float v0 = acc[m][r] + bias; v0 = v0>0.f ? v0 : 0.f;
      xs[row*264 + wave*16 + l16] = f2bf(v0);
    }
  }
  __syncthreads();

  f32x4 acc2[4];
  #pragma unroll
  for (int m=0;m<4;m++) acc2[m]=(f32x4){0,0,0,0};
  #pragma unroll
  for (int ks=0;ks<4;ks++){
    #pragma unroll
    for (int m=0;m<4;m++){
      short8 av = *(const short8*)(&xs[(m*16+l16)*264 + ks*32 + quad*8]);
      acc2[m] = __builtin_amdgcn_mfma_f32_16x16x32_bf16(av, wb2[ks], acc2[m],0,0,0);
    }
  }
  float c0 = b2[wave*16 + l16];
  #pragma unroll
  for (int m=0;m<4;m++){
    #pragma unroll
    for (int r=0;r<4;r++){
      int node = node0 + m*16 + quad*4 + r;
      if (node<n){
        float v0 = acc2[m][r]+c0; v0 = v0>0.f?v0:0.f;
        out[(size_t)node*128 + wave*16 + l16] = v0;
      }
    }
  }
}

extern "C" void kernel_launch(void* const* d_in, const int* in_sizes, int n_in,
                              void* d_out, int out_size, void* d_ws, size_t ws_size,
                              hipStream_t stream){
  const float* h  = (const float*)d_in[0];
  const int*   ei = (const int*)d_in[1];
  const float* W1 = (const float*)d_in[2];
  const float* b1 = (const float*)d_in[3];
  const float* W2 = (const float*)d_in[4];
  const float* b2 = (const float*)d_in[5];
  float* out = (float*)d_out;
  u32* outw  = (u32*)d_out;
  int n  = in_sizes[0] / 128;
  int nE = in_sizes[1] / 2;
  const int* srcI = ei;
  const int* dstI = ei + nE;
  int nbuck = (n + BKT_NODES - 1) >> BKT_SHIFT;   // 782

  // workspace layout — ~18 MB (recs + gcnt + hbf + transposed weights)
  char* ws = (char*)d_ws;
  u32* recs = (u32*)ws;                               // nbuck*CAP*4 = 4.80 MB
  size_t off = (size_t)nbuck*CAP*4;
  int* gcnt = (int*)(ws + off); off += 4096;          // NBH ints
  u16* hbf  = (u16*)(ws + off); off += (size_t)n*256; // n x 128 bf16 = 12.8 MB
  off = (off + 15) & ~(size_t)15;
  u16* w1t  = (u16*)(ws + off);                       // 128x256 bf16
  u16* w2t  = (u16*)(ws + off + 65536);               // 128x128 bf16

  hipMemsetAsync(gcnt, 0, NBH*sizeof(int), stream);
  int gB = (nE + EPB - 1)/EPB;                        // 196 bin blocks (first)
  int nh8 = n*16;
  int castN = nh8 > 49152 ? nh8 : 49152;
  int gC = (castN + 255)/256;
  k_castbin<<<gB+gC, 256, 0, stream>>>(srcI, dstI, gcnt, recs, nE, gB,
                                       h, hbf, nh8, W1, W2, w1t, w2t);
  k_aggf<<<nbuck, 512, 0, stream>>>((const u32*)hbf, recs, gcnt, outw, n);
  k_mlp<<<nbuck, 512, 0, stream>>>(hbf, outw, w1t, w2t, b1, b2, out, n);
}